// Round 10
// baseline (424.249 us; speedup 1.0000x reference)
//
#include <hip/hip_runtime.h>
#include <math.h>

#define BATCH   4
#define SEQLEN  4096
#define DMODEL  256
#define DINNER  1024
#define NHEADS  16
#define HEADDIM 64
#define DSTATE  64
#define CONVDIM 1152
#define DPROJ   2192
#define NCHUNK  64
#define CHUNK   64
#define ROWS    (BATCH*SEQLEN)   // 16384
#define NPAD1   2304             // DPROJ padded to multiple of 128
#define TS      72               // padded LDS row stride (u16) for 64-wide tiles

typedef unsigned short u16;
using frag  = __attribute__((ext_vector_type(8))) short;   // 8 bf16 (4 VGPRs)
using f32x4 = __attribute__((ext_vector_type(4))) float;
using u32x4 = __attribute__((ext_vector_type(4))) unsigned int;

// bf16 <-> f32 helpers (storage-only precision loss, RNE rounding)
static __device__ __forceinline__ float bf2f(u16 u) {
    return __uint_as_float(((unsigned int)u) << 16);
}
static __device__ __forceinline__ u16 f2bf(float f) {
    unsigned int x = __float_as_uint(f);
    x += 0x7fffu + ((x >> 16) & 1u);
    return (u16)(x >> 16);
}
// non-temporal 16B store (no read-for-ownership, evict-first)
static __device__ __forceinline__ void nt_store16(void* p, uint4 v) {
    u32x4 t = {v.x, v.y, v.z, v.w};
    __builtin_nontemporal_store(t, (u32x4*)p);
}

// ---------------------------------------------------------------------------
// fp32 -> bf16 convert (4 elems/thread). Rows >= valid_rows write zeros
// ---------------------------------------------------------------------------
__global__ __launch_bounds__(256) void cvt_bf16(const float* __restrict__ in,
                                                u16* __restrict__ out,
                                                int total4, int valid_rows, int colshift)
{
    const int i = blockIdx.x * 256 + threadIdx.x;
    if (i >= total4) return;
    const int e = i * 4;
    const int row = e >> colshift;
    ushort4 o;
    if (row < valid_rows) {
        float4 v = *(const float4*)(in + e);
        o.x = f2bf(v.x); o.y = f2bf(v.y); o.z = f2bf(v.z); o.w = f2bf(v.w);
    } else {
        o.x = 0; o.y = 0; o.z = 0; o.w = 0;
    }
    *(ushort4*)(out + e) = o;
}

// ---------------------------------------------------------------------------
// bf16 MFMA GEMM: C[M][N] = A[M][KTOT] @ W[N][KTOT]^T
// 128x128 tile, BK=64, 4 waves. LDS k-slots XOR-swizzled by (row&7).
// SCALE_A: fused RMSNorm on A rows (normv = sum of squares, nw = norm weight).
// All C stores non-temporal.
// ---------------------------------------------------------------------------
template<int KTOT, bool C_BF, bool SCALE_A>
__global__ __launch_bounds__(256) void gemm_mfma(const u16* __restrict__ A,
                                                 const u16* __restrict__ W,
                                                 void* __restrict__ Cp,
                                                 int N,
                                                 const float* __restrict__ normv,
                                                 const float* __restrict__ nw)
{
    __shared__ u16 pool[128*136];          // staging uses first 32 KB
    u16* As = pool;
    u16* Ws = pool + 128*64;

    const int m0 = blockIdx.y * 128;
    const int n0 = blockIdx.x * 128;
    const int tid = threadIdx.x;
    const int lane = tid & 63;
    const int w  = tid >> 6;
    const int wr = w >> 1, wc = w & 1;

    const int srow = tid >> 3;             // 0..31
    const int scol = (tid & 7) * 8;        // 0..56
    const int ssw  = scol ^ ((srow & 7) * 8);

    const int lrow = lane & 15;
    const int kgrp = lane >> 4;
    const int swz  = (lrow & 7) * 8;

    float ascale[4];
    if constexpr (SCALE_A) {
        #pragma unroll
        for (int it = 0; it < 4; ++it)
            ascale[it] = rsqrtf(normv[m0 + it*32 + srow] * (1.f/1024.f) + 1e-5f);
    }

    f32x4 acc[4][4] = {};

    uint4 ra[4], rw[4];
    #pragma unroll
    for (int it = 0; it < 4; ++it) {
        const int r = it*32 + srow;
        ra[it] = *(const uint4*)(A + (size_t)(m0 + r)*KTOT + scol);
        rw[it] = *(const uint4*)(W + (size_t)(n0 + r)*KTOT + scol);
    }

    for (int kt = 0; kt < KTOT; kt += 64) {
        __syncthreads();
        #pragma unroll
        for (int it = 0; it < 4; ++it) {
            const int r = it*32 + srow;
            if constexpr (SCALE_A) {
                uint4 v = ra[it];
                unsigned int* pw = (unsigned int*)&v;
                const float* nwp = nw + kt + scol;
                #pragma unroll
                for (int q = 0; q < 4; ++q) {
                    const float lo = bf2f((u16)(pw[q] & 0xffff)) * ascale[it] * nwp[2*q];
                    const float hi = bf2f((u16)(pw[q] >> 16))    * ascale[it] * nwp[2*q+1];
                    pw[q] = (unsigned int)f2bf(lo) | ((unsigned int)f2bf(hi) << 16);
                }
                *(uint4*)&As[r*64 + ssw] = v;
            } else {
                *(uint4*)&As[r*64 + ssw] = ra[it];
            }
            *(uint4*)&Ws[r*64 + ssw] = rw[it];
        }
        __syncthreads();
        if (kt + 64 < KTOT) {
            #pragma unroll
            for (int it = 0; it < 4; ++it) {
                const int r = it*32 + srow;
                ra[it] = *(const uint4*)(A + (size_t)(m0 + r)*KTOT + kt + 64 + scol);
                rw[it] = *(const uint4*)(W + (size_t)(n0 + r)*KTOT + kt + 64 + scol);
            }
        }
        #pragma unroll
        for (int ks = 0; ks < 2; ++ks) {
            const int kx = (ks*32 + kgrp*8) ^ swz;
            frag af[4], bf[4];
            #pragma unroll
            for (int i = 0; i < 4; ++i)
                af[i] = *(const frag*)&As[(wr*64 + i*16 + lrow)*64 + kx];
            #pragma unroll
            for (int j = 0; j < 4; ++j)
                bf[j] = *(const frag*)&Ws[(wc*64 + j*16 + lrow)*64 + kx];
            #pragma unroll
            for (int i = 0; i < 4; ++i)
                #pragma unroll
                for (int j = 0; j < 4; ++j)
                    acc[i][j] = __builtin_amdgcn_mfma_f32_16x16x32_bf16(af[i], bf[j], acc[i][j], 0, 0, 0);
        }
    }

    if constexpr (C_BF) {
        __syncthreads();
        #pragma unroll
        for (int i = 0; i < 4; ++i)
            #pragma unroll
            for (int j = 0; j < 4; ++j)
                #pragma unroll
                for (int r = 0; r < 4; ++r)
                    pool[(wr*64 + i*16 + kgrp*4 + r)*136 + wc*64 + j*16 + lrow] =
                        f2bf(acc[i][j][r]);
        __syncthreads();
        #pragma unroll
        for (int q = 0; q < 8; ++q) {
            const int f  = q*2048 + tid*8;
            const int rl = f >> 7;
            const int cl = f & 127;
            const int col = n0 + cl;
            if (col < N)
                nt_store16((u16*)Cp + (size_t)(m0 + rl)*N + col,
                           *(const uint4*)&pool[rl*136 + cl]);
        }
    } else {
        #pragma unroll
        for (int i = 0; i < 4; ++i) {
            #pragma unroll
            for (int j = 0; j < 4; ++j) {
                const int col = n0 + wc*64 + j*16 + lrow;
                if (col < N) {
                    #pragma unroll
                    for (int r = 0; r < 4; ++r) {
                        const int row = m0 + wr*64 + i*16 + kgrp*4 + r;
                        __builtin_nontemporal_store(acc[i][j][r],
                            (float*)Cp + (size_t)row * N + col);
                    }
                }
            }
        }
    }
}

// ---------------------------------------------------------------------------
// Depthwise causal conv (W=4) + bias + SiLU  (nt store)
// ---------------------------------------------------------------------------
__global__ __launch_bounds__(256) void conv_kernel(const u16* __restrict__ zxbcdt,
                                                   const float* __restrict__ conv_w,
                                                   const float* __restrict__ conv_b,
                                                   u16* __restrict__ xconv)
{
    const int idx = blockIdx.x * 256 + threadIdx.x;
    const int ch  = idx % CONVDIM;
    const int row = idx / CONVDIM;
    const int l   = row & (SEQLEN-1);
    const int b   = row >> 12;

    float acc = conv_b[ch];
    #pragma unroll
    for (int w = 0; w < 4; ++w) {
        const int ls = l - 3 + w;
        if (ls >= 0) {
            acc += bf2f(zxbcdt[(size_t)(b*SEQLEN + ls) * DPROJ + DINNER + ch]) * conv_w[ch*4 + w];
        }
    }
    __builtin_nontemporal_store(f2bf(acc / (1.f + __expf(-acc))), xconv + idx);
}

// ---------------------------------------------------------------------------
// SSD phase A (MFMA, fused dt/softplus):
//   dt = softplus(zxbcdt[...,-16+h]+bias); dA = -exp(A_log)*dt (wave-0 scan)
//   G = C @ B^T ; M = tril(G)*exp(acs_i - acs_j)
//   Y_diag = M @ xdt -> ybuf ; S^T = xdt^T @ Bscaled -> statesT [p][n]
// Outputs re-staged in dead LDS tiles -> coalesced nt stores.
// ---------------------------------------------------------------------------
__global__ __launch_bounds__(256) void ssd_phaseA(const u16* __restrict__ xconv,
                                                  const u16* __restrict__ zxbcdt,
                                                  const float* __restrict__ dt_bias,
                                                  const float* __restrict__ A_log,
                                                  u16* __restrict__ ybuf,
                                                  u16* __restrict__ statesT,
                                                  float* __restrict__ acs_g,
                                                  float* __restrict__ asum_g)
{
    const int h = blockIdx.x, c = blockIdx.y, b = blockIdx.z;
    const int tid = threadIdx.x;
    const int lane = tid & 63;
    const int w = tid >> 6;
    const int l0 = c * CHUNK;

    __shared__ u16 CtM[64*TS];   // C tile -> M (own rows) -> Y (own rows)
    __shared__ u16 Bt [64*TS];   // B row-major [j][n]
    __shared__ u16 BtT[64*TS];   // decay-scaled B^T [n][j^swz]
    __shared__ u16 xdtT[64*TS];  // (x*dt)^T [p][j^swz] -> S (own rows)
    __shared__ float a_cs[64];
    __shared__ float a_dt[64];

    // fused dt + inclusive cumsum of dA (wave 0)
    if (w == 0) {
        const float raw = bf2f(zxbcdt[(size_t)(b*SEQLEN + l0 + lane)*DPROJ + (DPROJ - NHEADS) + h])
                        + dt_bias[h];
        const float sp = (raw > 20.f) ? raw : log1pf(__expf(raw));
        a_dt[lane] = sp;
        float v = -__expf(A_log[h]) * sp;
        #pragma unroll
        for (int o = 1; o < 64; o <<= 1) {
            float t = __shfl_up(v, o, 64);
            if (lane >= o) v += t;
        }
        a_cs[lane] = v;
    }
    __syncthreads();
    const float a_last = a_cs[63];

    // staging: thread t -> row j = t>>2, 16-col block q0 = (t&3)*16
    {
        const int j  = tid >> 2;
        const int q0 = (tid & 3) * 16;
        const u16* rp = xconv + (size_t)(b*SEQLEN + l0 + j) * CONVDIM;
        const float dtv = a_dt[j];
        const float dec = __expf(a_last - a_cs[j]);

        *(uint4*)&CtM[j*TS + q0]     = *(const uint4*)(rp + DINNER + DSTATE + q0);
        *(uint4*)&CtM[j*TS + q0 + 8] = *(const uint4*)(rp + DINNER + DSTATE + q0 + 8);

        uint4 b0 = *(const uint4*)(rp + DINNER + q0);
        uint4 b1 = *(const uint4*)(rp + DINNER + q0 + 8);
        *(uint4*)&Bt[j*TS + q0]     = b0;
        *(uint4*)&Bt[j*TS + q0 + 8] = b1;
        unsigned int bw[8] = {b0.x, b0.y, b0.z, b0.w, b1.x, b1.y, b1.z, b1.w};
        #pragma unroll
        for (int s = 0; s < 8; ++s) {
            const int n0 = q0 + 2*s, n1 = n0 + 1;
            BtT[n0*TS + (j ^ (n0 & 0x38))] = f2bf(bf2f((u16)(bw[s] & 0xffff)) * dec);
            BtT[n1*TS + (j ^ (n1 & 0x38))] = f2bf(bf2f((u16)(bw[s] >> 16))    * dec);
        }

        uint4 x0 = *(const uint4*)(rp + h*HEADDIM + q0);
        uint4 x1 = *(const uint4*)(rp + h*HEADDIM + q0 + 8);
        unsigned int xw[8] = {x0.x, x0.y, x0.z, x0.w, x1.x, x1.y, x1.z, x1.w};
        #pragma unroll
        for (int s = 0; s < 8; ++s) {
            const int p0 = q0 + 2*s, p1 = p0 + 1;
            xdtT[p0*TS + (j ^ (p0 & 0x38))] = f2bf(bf2f((u16)(xw[s] & 0xffff)) * dtv);
            xdtT[p1*TS + (j ^ (p1 & 0x38))] = f2bf(bf2f((u16)(xw[s] >> 16))    * dtv);
        }
    }
    __syncthreads();

    const int lrow = lane & 15;
    const int kgrp = lane >> 4;

    // ---- G = C @ B^T ----
    f32x4 accG[4] = {};
    #pragma unroll
    for (int ks = 0; ks < 2; ++ks) {
        frag a = *(const frag*)&CtM[(w*16 + lrow)*TS + ks*32 + kgrp*8];
        #pragma unroll
        for (int cf = 0; cf < 4; ++cf) {
            frag bb = *(const frag*)&Bt[(cf*16 + lrow)*TS + ks*32 + kgrp*8];
            accG[cf] = __builtin_amdgcn_mfma_f32_16x16x32_bf16(a, bb, accG[cf], 0, 0, 0);
        }
    }

    // ---- mask + decay -> M over own C rows ----
    {
        float aj[4];
        #pragma unroll
        for (int cf = 0; cf < 4; ++cf) aj[cf] = a_cs[cf*16 + lrow];
        #pragma unroll
        for (int r = 0; r < 4; ++r) {
            const int i = w*16 + kgrp*4 + r;
            const float ai = a_cs[i];
            #pragma unroll
            for (int cf = 0; cf < 4; ++cf) {
                const int jcol = cf*16 + lrow;
                const float g = (jcol <= i) ? accG[cf][r] * __expf(ai - aj[cf]) : 0.f;
                CtM[i*TS + jcol] = f2bf(g);
            }
        }
    }

    // ---- Y_diag = M @ xdt ----
    f32x4 accY[4] = {};
    #pragma unroll
    for (int ks = 0; ks < 2; ++ks) {
        frag a = *(const frag*)&CtM[(w*16 + lrow)*TS + ks*32 + kgrp*8];
        #pragma unroll
        for (int cf = 0; cf < 4; ++cf) {
            const int p = cf*16 + lrow;
            frag bb = *(const frag*)&xdtT[p*TS + ((ks*32 + kgrp*8) ^ (p & 0x38))];
            accY[cf] = __builtin_amdgcn_mfma_f32_16x16x32_bf16(a, bb, accY[cf], 0, 0, 0);
        }
    }
    // Y -> own CtM rows (wave-local; CtM not read by other waves)
    #pragma unroll
    for (int r = 0; r < 4; ++r) {
        const int i = w*16 + kgrp*4 + r;
        #pragma unroll
        for (int cf = 0; cf < 4; ++cf)
            CtM[i*TS + cf*16 + lrow] = f2bf(accY[cf][r]);
    }

    // ---- S^T = xdt^T @ Bscaled ----
    f32x4 accS[4] = {};
    #pragma unroll
    for (int ks = 0; ks < 2; ++ks) {
        const int pr = w*16 + lrow;
        frag a = *(const frag*)&xdtT[pr*TS + ((ks*32 + kgrp*8) ^ (pr & 0x38))];
        #pragma unroll
        for (int cf = 0; cf < 4; ++cf) {
            const int n = cf*16 + lrow;
            frag bb = *(const frag*)&BtT[n*TS + ((ks*32 + kgrp*8) ^ (n & 0x38))];
            accS[cf] = __builtin_amdgcn_mfma_f32_16x16x32_bf16(a, bb, accS[cf], 0, 0, 0);
        }
    }
    __syncthreads();   // all accY/accS xdtT reads complete before overwrite
    #pragma unroll
    for (int r = 0; r < 4; ++r) {
        const int p = w*16 + kgrp*4 + r;
        #pragma unroll
        for (int cf = 0; cf < 4; ++cf)
            xdtT[p*TS + cf*16 + lrow] = f2bf(accS[cf][r]);   // linear [p][n]
    }
    __syncthreads();

    // coalesced nt write-out: Y (from CtM), S (from xdtT)
    {
        const int rr = tid >> 2;
        const int q  = (tid & 3) * 16;
        u16* yg = ybuf + (size_t)(b*SEQLEN + l0 + rr)*DINNER + h*HEADDIM + q;
        nt_store16(yg,     *(const uint4*)&CtM[rr*TS + q]);
        nt_store16(yg + 8, *(const uint4*)&CtM[rr*TS + q + 8]);
        u16* sg = statesT + (((size_t)b*NCHUNK + c)*NHEADS + h)*4096 + tid*16;
        nt_store16(sg,     *(const uint4*)&xdtT[rr*TS + q]);
        nt_store16(sg + 8, *(const uint4*)&xdtT[rr*TS + q + 8]);
    }

    if (tid < 64) acs_g[(((size_t)b*NCHUNK + c)*NHEADS + h)*CHUNK + tid] = a_cs[tid];
    if (tid == 0) asum_g[((size_t)b*NHEADS + h)*NCHUNK + c] = a_last;
}

// ---------------------------------------------------------------------------
// Inter-chunk scan, in place over statesT ([p][n] layout, elementwise)
// ---------------------------------------------------------------------------
__global__ __launch_bounds__(256) void ssd_scan(u16* __restrict__ statesT,
                                                const float* __restrict__ asum_g)
{
    const int gid = blockIdx.x;
    const int s = gid & 15;
    const int h = (gid >> 4) & (NHEADS-1);
    const int b = gid >> 8;
    const int elem = s*256 + threadIdx.x;

    const float* as = asum_g + ((size_t)b*NHEADS + h)*NCHUNK;
    float P = 0.f;
    for (int c = 0; c < NCHUNK; ++c) {
        const size_t idx = (((size_t)b*NCHUNK + c)*NHEADS + h)*4096 + elem;
        const float sv = bf2f(statesT[idx]);
        statesT[idx] = f2bf(P);
        P = P * __expf(as[c]) + sv;
    }
}

// ---------------------------------------------------------------------------
// SSD phase C (MFMA): Y = Y_diag + exp(a_cs)*(C @ Sp) + x*D ; y *= silu(z)
// Also accumulates per-row sum(y^2) into normbuf (fused RMSNorm, part 1).
// ---------------------------------------------------------------------------
__global__ __launch_bounds__(256) void ssd_phaseC(const u16* __restrict__ xconv,
                                                  const u16* __restrict__ zxbcdt,
                                                  const u16* __restrict__ statesT,
                                                  const float* __restrict__ acs_g,
                                                  const float* __restrict__ Dvec,
                                                  u16* __restrict__ ybuf,
                                                  float* __restrict__ normbuf)
{
    const int h = blockIdx.x, c = blockIdx.y, b = blockIdx.z;
    const int tid = threadIdx.x;
    const int lane = tid & 63;
    const int w = tid >> 6;
    const int l0 = c * CHUNK;

    __shared__ u16 Ct [64*TS];
    __shared__ u16 SpT[64*TS];
    __shared__ float a_cs[64];

    if (tid < 64) a_cs[tid] = acs_g[(((size_t)b*NCHUNK + c)*NHEADS + h)*CHUNK + tid];
    {
        const int r  = tid >> 2;
        const int q0 = (tid & 3) * 16;
        const u16* cp = xconv + (size_t)(b*SEQLEN + l0 + r)*CONVDIM + DINNER + DSTATE;
        *(uint4*)&Ct[r*TS + q0]     = *(const uint4*)(cp + q0);
        *(uint4*)&Ct[r*TS + q0 + 8] = *(const uint4*)(cp + q0 + 8);
        const u16* spg = statesT + (((size_t)b*NCHUNK + c)*NHEADS + h)*4096 + r*64;
        *(uint4*)&SpT[r*TS + q0]     = *(const uint4*)(spg + q0);
        *(uint4*)&SpT[r*TS + q0 + 8] = *(const uint4*)(spg + q0 + 8);
    }
    __syncthreads();

    const int lrow = lane & 15;
    const int kgrp = lane >> 4;

    f32x4 acc[4] = {};
    #pragma unroll
    for (int ks = 0; ks < 2; ++ks) {
        frag a = *(const frag*)&Ct[(w*16 + lrow)*TS + ks*32 + kgrp*8];
        #pragma unroll
        for (int cf = 0; cf < 4; ++cf) {
            frag bb = *(const frag*)&SpT[(cf*16 + lrow)*TS + ks*32 + kgrp*8];
            acc[cf] = __builtin_amdgcn_mfma_f32_16x16x32_bf16(a, bb, acc[cf], 0, 0, 0);
        }
    }

    const float Dh = Dvec[h];
    #pragma unroll
    for (int r = 0; r < 4; ++r) {
        const int i = w*16 + kgrp*4 + r;
        const int l = l0 + i;
        const float e = __expf(a_cs[i]);
        const u16* xr = xconv  + (size_t)(b*SEQLEN + l)*CONVDIM + h*HEADDIM;
        const u16* zr = zxbcdt + (size_t)(b*SEQLEN + l)*DPROJ   + h*HEADDIM;
        u16* yp = ybuf + (size_t)(b*SEQLEN + l)*DINNER + h*HEADDIM;
        float ssq = 0.f;
        #pragma unroll
        for (int cf = 0; cf < 4; ++cf) {
            const int p = cf*16 + lrow;
            const float yv = bf2f(yp[p]) + e*acc[cf][r] + bf2f(xr[p])*Dh;
            const float zv = bf2f(zr[p]);
            const float fin = yv * (zv / (1.f + __expf(-zv)));
            ssq += fin * fin;
            yp[p] = f2bf(fin);
        }
        // reduce ssq over the 16-lane group (covers 64 cols of this head)
        #pragma unroll
        for (int o = 1; o < 16; o <<= 1) ssq += __shfl_xor(ssq, o, 16);
        if (lrow == 0) atomicAdd(normbuf + (size_t)(b*SEQLEN + l), ssq);
    }
}

// ---------------------------------------------------------------------------
extern "C" void kernel_launch(void* const* d_in, const int* in_sizes, int n_in,
                              void* d_out, int out_size, void* d_ws, size_t ws_size,
                              hipStream_t stream)
{
    const float* u          = (const float*)d_in[0];
    const float* in_proj_w  = (const float*)d_in[1];
    const float* conv_w     = (const float*)d_in[2];
    const float* conv_b     = (const float*)d_in[3];
    const float* dt_bias    = (const float*)d_in[4];
    const float* A_log      = (const float*)d_in[5];
    const float* Dvec       = (const float*)d_in[6];
    const float* norm_w     = (const float*)d_in[7];
    const float* out_proj_w = (const float*)d_in[8];
    float* out = (float*)d_out;

    // workspace layout
    float* acs     = (float*)d_ws;                                 // B*NC*H*CHUNK
    float* asum    = acs  + (size_t)BATCH*NCHUNK*NHEADS*CHUNK;     // B*H*NC
    float* normbuf = asum + (size_t)BATCH*NHEADS*NCHUNK;           // ROWS
    u16* zxbcdt = (u16*)(normbuf + (size_t)ROWS);
    u16* xconv  = zxbcdt + (size_t)ROWS*DPROJ;
    u16* ybuf   = xconv  + (size_t)ROWS*CONVDIM;
    u16* states = ybuf   + (size_t)ROWS*DINNER;                    // B*NC*H*64*64
    u16* w2b    = states + (size_t)BATCH*NCHUNK*NHEADS*DSTATE*HEADDIM;
    // overlay: u_bf + w1b live inside states (dead until ssd_phaseA)
    u16* u_bf   = states;                          // 16384*256
    u16* w1b    = states + (size_t)ROWS*DMODEL;    // 2304*256 (zero-padded rows)

    hipMemsetAsync(normbuf, 0, ROWS*sizeof(float), stream);

    cvt_bf16<<<(ROWS*DMODEL/4+255)/256, 256, 0, stream>>>(u, u_bf, ROWS*DMODEL/4, ROWS, 8);
    cvt_bf16<<<(NPAD1*DMODEL/4+255)/256, 256, 0, stream>>>(in_proj_w, w1b, NPAD1*DMODEL/4, DPROJ, 8);
    cvt_bf16<<<(DMODEL*DINNER/4+255)/256, 256, 0, stream>>>(out_proj_w, w2b, DMODEL*DINNER/4, DMODEL, 10);

    gemm_mfma<DMODEL, true, false><<<dim3(NPAD1/128, ROWS/128), 256, 0, stream>>>(
        u_bf, w1b, zxbcdt, DPROJ, nullptr, nullptr);

    conv_kernel<<<(ROWS*CONVDIM)/256, 256, 0, stream>>>(zxbcdt, conv_w, conv_b, xconv);
    ssd_phaseA<<<dim3(NHEADS, NCHUNK, BATCH), 256, 0, stream>>>(
        xconv, zxbcdt, dt_bias, A_log, ybuf, states, acs, asum);
    ssd_scan<<<BATCH*NHEADS*16, 256, 0, stream>>>(states, asum);
    ssd_phaseC<<<dim3(NHEADS, NCHUNK, BATCH), 256, 0, stream>>>(
        xconv, zxbcdt, states, acs, Dvec, ybuf, normbuf);

    gemm_mfma<DINNER, false, true><<<dim3(DMODEL/128, ROWS/128), 256, 0, stream>>>(
        ybuf, w2b, out, DMODEL, normbuf, norm_w);
}

// Round 11
// 390.040 us; speedup vs baseline: 1.0877x; 1.0877x over previous
//
#include <hip/hip_runtime.h>
#include <math.h>

#define BATCH   4
#define SEQLEN  4096
#define DMODEL  256
#define DINNER  1024
#define NHEADS  16
#define HEADDIM 64
#define DSTATE  64
#define CONVDIM 1152
#define DPROJ   2192
#define NCHUNK  64
#define CHUNK   64
#define ROWS    (BATCH*SEQLEN)   // 16384
#define NPAD1   2304             // DPROJ padded to multiple of 128
#define TS      72               // padded LDS row stride (u16) for 64-wide tiles

typedef unsigned short u16;
using frag  = __attribute__((ext_vector_type(8))) short;   // 8 bf16 (4 VGPRs)
using f32x4 = __attribute__((ext_vector_type(4))) float;
using u32x4 = __attribute__((ext_vector_type(4))) unsigned int;

// bf16 <-> f32 helpers (storage-only precision loss, RNE rounding)
static __device__ __forceinline__ float bf2f(u16 u) {
    return __uint_as_float(((unsigned int)u) << 16);
}
static __device__ __forceinline__ u16 f2bf(float f) {
    unsigned int x = __float_as_uint(f);
    x += 0x7fffu + ((x >> 16) & 1u);
    return (u16)(x >> 16);
}
static __device__ __forceinline__ unsigned int pk2(float lo, float hi) {
    return (unsigned int)f2bf(lo) | ((unsigned int)f2bf(hi) << 16);
}
// non-temporal 16B store (no read-for-ownership, evict-first)
static __device__ __forceinline__ void nt_store16(void* p, uint4 v) {
    u32x4 t = {v.x, v.y, v.z, v.w};
    __builtin_nontemporal_store(t, (u32x4*)p);
}

// ---------------------------------------------------------------------------
// fp32 -> bf16 convert (4 elems/thread). Rows >= valid_rows write zeros
// ---------------------------------------------------------------------------
__global__ __launch_bounds__(256) void cvt_bf16(const float* __restrict__ in,
                                                u16* __restrict__ out,
                                                int total4, int valid_rows, int colshift)
{
    const int i = blockIdx.x * 256 + threadIdx.x;
    if (i >= total4) return;
    const int e = i * 4;
    const int row = e >> colshift;
    ushort4 o;
    if (row < valid_rows) {
        float4 v = *(const float4*)(in + e);
        o.x = f2bf(v.x); o.y = f2bf(v.y); o.z = f2bf(v.z); o.w = f2bf(v.w);
    } else {
        o.x = 0; o.y = 0; o.z = 0; o.w = 0;
    }
    *(ushort4*)(out + e) = o;
}

// ---------------------------------------------------------------------------
// bf16 MFMA GEMM: C[M][N] = A[M][KTOT] @ W[N][KTOT]^T
// 128x128 tile, BK=64, 4 waves. LDS k-slots XOR-swizzled by (row&7).
// XCD-aware bijective block swizzle: blocks sharing an A-panel -> same XCD.
// A_F32: A is fp32, converted to bf16 at LDS-stage (bit-identical to cvt).
// SCALE_A: fused RMSNorm on A rows. All C stores non-temporal.
// ---------------------------------------------------------------------------
template<int KTOT, bool C_BF, bool SCALE_A, bool A_F32>
__global__ __launch_bounds__(256) void gemm_mfma(const void* __restrict__ Ap,
                                                 const u16* __restrict__ W,
                                                 void* __restrict__ Cp,
                                                 int N,
                                                 const float* __restrict__ normv,
                                                 const float* __restrict__ nw)
{
    __shared__ u16 pool[128*136];          // staging uses first 32 KB
    u16* As = pool;
    u16* Ws = pool + 128*64;

    // bijective XCD swizzle (nwg % 8 == 0 for all our grids)
    const int gx   = gridDim.x;
    const int nwg  = gx * gridDim.y;
    const int flat = blockIdx.y * gx + blockIdx.x;
    const int swzb = (flat & 7) * (nwg >> 3) + (flat >> 3);
    const int m0 = (swzb / gx) * 128;
    const int n0 = (swzb % gx) * 128;

    const float* Af = (const float*)Ap;
    const u16*   Ab = (const u16*)Ap;

    const int tid = threadIdx.x;
    const int lane = tid & 63;
    const int w  = tid >> 6;
    const int wr = w >> 1, wc = w & 1;

    const int srow = tid >> 3;             // 0..31
    const int scol = (tid & 7) * 8;        // 0..56
    const int ssw  = scol ^ ((srow & 7) * 8);

    const int lrow = lane & 15;
    const int kgrp = lane >> 4;
    const int swz  = (lrow & 7) * 8;

    float ascale[4];
    if constexpr (SCALE_A) {
        #pragma unroll
        for (int it = 0; it < 4; ++it)
            ascale[it] = rsqrtf(normv[m0 + it*32 + srow] * (1.f/1024.f) + 1e-5f);
    }

    f32x4 acc[4][4] = {};

    uint4 ra[4], rw[4];
    float4 raf[4][2];
    #pragma unroll
    for (int it = 0; it < 4; ++it) {
        const int r = it*32 + srow;
        if constexpr (A_F32) {
            raf[it][0] = *(const float4*)(Af + (size_t)(m0 + r)*KTOT + scol);
            raf[it][1] = *(const float4*)(Af + (size_t)(m0 + r)*KTOT + scol + 4);
        } else {
            ra[it] = *(const uint4*)(Ab + (size_t)(m0 + r)*KTOT + scol);
        }
        rw[it] = *(const uint4*)(W + (size_t)(n0 + r)*KTOT + scol);
    }

    for (int kt = 0; kt < KTOT; kt += 64) {
        __syncthreads();
        #pragma unroll
        for (int it = 0; it < 4; ++it) {
            const int r = it*32 + srow;
            if constexpr (A_F32) {
                uint4 v;
                v.x = pk2(raf[it][0].x, raf[it][0].y);
                v.y = pk2(raf[it][0].z, raf[it][0].w);
                v.z = pk2(raf[it][1].x, raf[it][1].y);
                v.w = pk2(raf[it][1].z, raf[it][1].w);
                *(uint4*)&As[r*64 + ssw] = v;
            } else if constexpr (SCALE_A) {
                uint4 v = ra[it];
                unsigned int* pw = (unsigned int*)&v;
                const float* nwp = nw + kt + scol;
                #pragma unroll
                for (int q = 0; q < 4; ++q) {
                    const float lo = bf2f((u16)(pw[q] & 0xffff)) * ascale[it] * nwp[2*q];
                    const float hi = bf2f((u16)(pw[q] >> 16))    * ascale[it] * nwp[2*q+1];
                    pw[q] = pk2(lo, hi);
                }
                *(uint4*)&As[r*64 + ssw] = v;
            } else {
                *(uint4*)&As[r*64 + ssw] = ra[it];
            }
            *(uint4*)&Ws[r*64 + ssw] = rw[it];
        }
        __syncthreads();
        if (kt + 64 < KTOT) {
            #pragma unroll
            for (int it = 0; it < 4; ++it) {
                const int r = it*32 + srow;
                if constexpr (A_F32) {
                    raf[it][0] = *(const float4*)(Af + (size_t)(m0 + r)*KTOT + kt + 64 + scol);
                    raf[it][1] = *(const float4*)(Af + (size_t)(m0 + r)*KTOT + kt + 64 + scol + 4);
                } else {
                    ra[it] = *(const uint4*)(Ab + (size_t)(m0 + r)*KTOT + kt + 64 + scol);
                }
                rw[it] = *(const uint4*)(W + (size_t)(n0 + r)*KTOT + kt + 64 + scol);
            }
        }
        #pragma unroll
        for (int ks = 0; ks < 2; ++ks) {
            const int kx = (ks*32 + kgrp*8) ^ swz;
            frag af[4], bf[4];
            #pragma unroll
            for (int i = 0; i < 4; ++i)
                af[i] = *(const frag*)&As[(wr*64 + i*16 + lrow)*64 + kx];
            #pragma unroll
            for (int j = 0; j < 4; ++j)
                bf[j] = *(const frag*)&Ws[(wc*64 + j*16 + lrow)*64 + kx];
            #pragma unroll
            for (int i = 0; i < 4; ++i)
                #pragma unroll
                for (int j = 0; j < 4; ++j)
                    acc[i][j] = __builtin_amdgcn_mfma_f32_16x16x32_bf16(af[i], bf[j], acc[i][j], 0, 0, 0);
        }
    }

    if constexpr (C_BF) {
        __syncthreads();
        #pragma unroll
        for (int i = 0; i < 4; ++i)
            #pragma unroll
            for (int j = 0; j < 4; ++j)
                #pragma unroll
                for (int r = 0; r < 4; ++r)
                    pool[(wr*64 + i*16 + kgrp*4 + r)*136 + wc*64 + j*16 + lrow] =
                        f2bf(acc[i][j][r]);
        __syncthreads();
        #pragma unroll
        for (int q = 0; q < 8; ++q) {
            const int f  = q*2048 + tid*8;
            const int rl = f >> 7;
            const int cl = f & 127;
            const int col = n0 + cl;
            if (col < N)
                nt_store16((u16*)Cp + (size_t)(m0 + rl)*N + col,
                           *(const uint4*)&pool[rl*136 + cl]);
        }
    } else {
        #pragma unroll
        for (int i = 0; i < 4; ++i) {
            #pragma unroll
            for (int j = 0; j < 4; ++j) {
                const int col = n0 + wc*64 + j*16 + lrow;
                if (col < N) {
                    #pragma unroll
                    for (int r = 0; r < 4; ++r) {
                        const int row = m0 + wr*64 + i*16 + kgrp*4 + r;
                        __builtin_nontemporal_store(acc[i][j][r],
                            (float*)Cp + (size_t)row * N + col);
                    }
                }
            }
        }
    }
}

// ---------------------------------------------------------------------------
// Depthwise causal conv (W=4) + bias + SiLU  (nt store)
// ---------------------------------------------------------------------------
__global__ __launch_bounds__(256) void conv_kernel(const u16* __restrict__ zxbcdt,
                                                   const float* __restrict__ conv_w,
                                                   const float* __restrict__ conv_b,
                                                   u16* __restrict__ xconv)
{
    const int idx = blockIdx.x * 256 + threadIdx.x;
    const int ch  = idx % CONVDIM;
    const int row = idx / CONVDIM;
    const int l   = row & (SEQLEN-1);
    const int b   = row >> 12;

    float acc = conv_b[ch];
    #pragma unroll
    for (int w = 0; w < 4; ++w) {
        const int ls = l - 3 + w;
        if (ls >= 0) {
            acc += bf2f(zxbcdt[(size_t)(b*SEQLEN + ls) * DPROJ + DINNER + ch]) * conv_w[ch*4 + w];
        }
    }
    __builtin_nontemporal_store(f2bf(acc / (1.f + __expf(-acc))), xconv + idx);
}

// ---------------------------------------------------------------------------
// SSD phase A (MFMA, fused dt/softplus, XCD-swizzled):
//   dt = softplus(zxbcdt[...,-16+h]+bias); dA = -exp(A_log)*dt (wave-0 scan)
//   G = C @ B^T ; M = tril(G)*exp(acs_i - acs_j)
//   Y_diag = M @ xdt -> ybuf ; S^T = xdt^T @ Bscaled -> statesT [p][n]
// Swizzle: all 16 heads of a chunk -> same XCD (B/C tile fetched once/XCD).
// ---------------------------------------------------------------------------
__global__ __launch_bounds__(256) void ssd_phaseA(const u16* __restrict__ xconv,
                                                  const u16* __restrict__ zxbcdt,
                                                  const float* __restrict__ dt_bias,
                                                  const float* __restrict__ A_log,
                                                  u16* __restrict__ ybuf,
                                                  u16* __restrict__ statesT,
                                                  float* __restrict__ acs_g,
                                                  float* __restrict__ asum_g)
{
    const int flat = blockIdx.x + NHEADS*(blockIdx.y + NCHUNK*blockIdx.z);
    const int swzb = (flat & 7) * (BATCH*NCHUNK*NHEADS/8) + (flat >> 3);
    const int h = swzb & (NHEADS-1);
    const int c = (swzb >> 4) & (NCHUNK-1);
    const int b = swzb >> 10;

    const int tid = threadIdx.x;
    const int lane = tid & 63;
    const int w = tid >> 6;
    const int l0 = c * CHUNK;

    __shared__ u16 CtM[64*TS];   // C tile -> M (own rows) -> Y (own rows)
    __shared__ u16 Bt [64*TS];   // B row-major [j][n]
    __shared__ u16 BtT[64*TS];   // decay-scaled B^T [n][j^swz]
    __shared__ u16 xdtT[64*TS];  // (x*dt)^T [p][j^swz] -> S (own rows)
    __shared__ float a_cs[64];
    __shared__ float a_dt[64];

    // fused dt + inclusive cumsum of dA (wave 0)
    if (w == 0) {
        const float raw = bf2f(zxbcdt[(size_t)(b*SEQLEN + l0 + lane)*DPROJ + (DPROJ - NHEADS) + h])
                        + dt_bias[h];
        const float sp = (raw > 20.f) ? raw : log1pf(__expf(raw));
        a_dt[lane] = sp;
        float v = -__expf(A_log[h]) * sp;
        #pragma unroll
        for (int o = 1; o < 64; o <<= 1) {
            float t = __shfl_up(v, o, 64);
            if (lane >= o) v += t;
        }
        a_cs[lane] = v;
    }
    __syncthreads();
    const float a_last = a_cs[63];

    // staging: thread t -> row j = t>>2, 16-col block q0 = (t&3)*16
    {
        const int j  = tid >> 2;
        const int q0 = (tid & 3) * 16;
        const u16* rp = xconv + (size_t)(b*SEQLEN + l0 + j) * CONVDIM;
        const float dtv = a_dt[j];
        const float dec = __expf(a_last - a_cs[j]);

        *(uint4*)&CtM[j*TS + q0]     = *(const uint4*)(rp + DINNER + DSTATE + q0);
        *(uint4*)&CtM[j*TS + q0 + 8] = *(const uint4*)(rp + DINNER + DSTATE + q0 + 8);

        uint4 b0 = *(const uint4*)(rp + DINNER + q0);
        uint4 b1 = *(const uint4*)(rp + DINNER + q0 + 8);
        *(uint4*)&Bt[j*TS + q0]     = b0;
        *(uint4*)&Bt[j*TS + q0 + 8] = b1;
        unsigned int bw[8] = {b0.x, b0.y, b0.z, b0.w, b1.x, b1.y, b1.z, b1.w};
        #pragma unroll
        for (int s = 0; s < 8; ++s) {
            const int n0 = q0 + 2*s, n1 = n0 + 1;
            BtT[n0*TS + (j ^ (n0 & 0x38))] = f2bf(bf2f((u16)(bw[s] & 0xffff)) * dec);
            BtT[n1*TS + (j ^ (n1 & 0x38))] = f2bf(bf2f((u16)(bw[s] >> 16))    * dec);
        }

        uint4 x0 = *(const uint4*)(rp + h*HEADDIM + q0);
        uint4 x1 = *(const uint4*)(rp + h*HEADDIM + q0 + 8);
        unsigned int xw[8] = {x0.x, x0.y, x0.z, x0.w, x1.x, x1.y, x1.z, x1.w};
        #pragma unroll
        for (int s = 0; s < 8; ++s) {
            const int p0 = q0 + 2*s, p1 = p0 + 1;
            xdtT[p0*TS + (j ^ (p0 & 0x38))] = f2bf(bf2f((u16)(xw[s] & 0xffff)) * dtv);
            xdtT[p1*TS + (j ^ (p1 & 0x38))] = f2bf(bf2f((u16)(xw[s] >> 16))    * dtv);
        }
    }
    __syncthreads();

    const int lrow = lane & 15;
    const int kgrp = lane >> 4;

    // ---- G = C @ B^T ----
    f32x4 accG[4] = {};
    #pragma unroll
    for (int ks = 0; ks < 2; ++ks) {
        frag a = *(const frag*)&CtM[(w*16 + lrow)*TS + ks*32 + kgrp*8];
        #pragma unroll
        for (int cf = 0; cf < 4; ++cf) {
            frag bb = *(const frag*)&Bt[(cf*16 + lrow)*TS + ks*32 + kgrp*8];
            accG[cf] = __builtin_amdgcn_mfma_f32_16x16x32_bf16(a, bb, accG[cf], 0, 0, 0);
        }
    }

    // ---- mask + decay -> M over own C rows ----
    {
        float aj[4];
        #pragma unroll
        for (int cf = 0; cf < 4; ++cf) aj[cf] = a_cs[cf*16 + lrow];
        #pragma unroll
        for (int r = 0; r < 4; ++r) {
            const int i = w*16 + kgrp*4 + r;
            const float ai = a_cs[i];
            #pragma unroll
            for (int cf = 0; cf < 4; ++cf) {
                const int jcol = cf*16 + lrow;
                const float g = (jcol <= i) ? accG[cf][r] * __expf(ai - aj[cf]) : 0.f;
                CtM[i*TS + jcol] = f2bf(g);
            }
        }
    }

    // ---- Y_diag = M @ xdt ----
    f32x4 accY[4] = {};
    #pragma unroll
    for (int ks = 0; ks < 2; ++ks) {
        frag a = *(const frag*)&CtM[(w*16 + lrow)*TS + ks*32 + kgrp*8];
        #pragma unroll
        for (int cf = 0; cf < 4; ++cf) {
            const int p = cf*16 + lrow;
            frag bb = *(const frag*)&xdtT[p*TS + ((ks*32 + kgrp*8) ^ (p & 0x38))];
            accY[cf] = __builtin_amdgcn_mfma_f32_16x16x32_bf16(a, bb, accY[cf], 0, 0, 0);
        }
    }
    // Y -> own CtM rows (wave-local; CtM not read by other waves)
    #pragma unroll
    for (int r = 0; r < 4; ++r) {
        const int i = w*16 + kgrp*4 + r;
        #pragma unroll
        for (int cf = 0; cf < 4; ++cf)
            CtM[i*TS + cf*16 + lrow] = f2bf(accY[cf][r]);
    }

    // ---- S^T = xdt^T @ Bscaled ----
    f32x4 accS[4] = {};
    #pragma unroll
    for (int ks = 0; ks < 2; ++ks) {
        const int pr = w*16 + lrow;
        frag a = *(const frag*)&xdtT[pr*TS + ((ks*32 + kgrp*8) ^ (pr & 0x38))];
        #pragma unroll
        for (int cf = 0; cf < 4; ++cf) {
            const int n = cf*16 + lrow;
            frag bb = *(const frag*)&BtT[n*TS + ((ks*32 + kgrp*8) ^ (n & 0x38))];
            accS[cf] = __builtin_amdgcn_mfma_f32_16x16x32_bf16(a, bb, accS[cf], 0, 0, 0);
        }
    }
    __syncthreads();   // all accY/accS xdtT reads complete before overwrite
    #pragma unroll
    for (int r = 0; r < 4; ++r) {
        const int p = w*16 + kgrp*4 + r;
        #pragma unroll
        for (int cf = 0; cf < 4; ++cf)
            xdtT[p*TS + cf*16 + lrow] = f2bf(accS[cf][r]);   // linear [p][n]
    }
    __syncthreads();

    // coalesced nt write-out: Y (from CtM), S (from xdtT)
    {
        const int rr = tid >> 2;
        const int q  = (tid & 3) * 16;
        u16* yg = ybuf + (size_t)(b*SEQLEN + l0 + rr)*DINNER + h*HEADDIM + q;
        nt_store16(yg,     *(const uint4*)&CtM[rr*TS + q]);
        nt_store16(yg + 8, *(const uint4*)&CtM[rr*TS + q + 8]);
        u16* sg = statesT + (((size_t)b*NCHUNK + c)*NHEADS + h)*4096 + tid*16;
        nt_store16(sg,     *(const uint4*)&xdtT[rr*TS + q]);
        nt_store16(sg + 8, *(const uint4*)&xdtT[rr*TS + q + 8]);
    }

    if (tid < 64) acs_g[(((size_t)b*NCHUNK + c)*NHEADS + h)*CHUNK + tid] = a_cs[tid];
    if (tid == 0) asum_g[((size_t)b*NHEADS + h)*NCHUNK + c] = a_last;
}

// ---------------------------------------------------------------------------
// Inter-chunk scan, in place over statesT ([p][n] layout, elementwise)
// ---------------------------------------------------------------------------
__global__ __launch_bounds__(256) void ssd_scan(u16* __restrict__ statesT,
                                                const float* __restrict__ asum_g)
{
    const int gid = blockIdx.x;
    const int s = gid & 15;
    const int h = (gid >> 4) & (NHEADS-1);
    const int b = gid >> 8;
    const int elem = s*256 + threadIdx.x;

    const float* as = asum_g + ((size_t)b*NHEADS + h)*NCHUNK;
    float P = 0.f;
    for (int c = 0; c < NCHUNK; ++c) {
        const size_t idx = (((size_t)b*NCHUNK + c)*NHEADS + h)*4096 + elem;
        const float sv = bf2f(statesT[idx]);
        statesT[idx] = f2bf(P);
        P = P * __expf(as[c]) + sv;
    }
}

// ---------------------------------------------------------------------------
// SSD phase C (MFMA, XCD-swizzled): Y = Y_diag + exp(a_cs)*(C @ Sp) + x*D ;
// y *= silu(z). Accumulates per-row sum(y^2) into normbuf (fused RMSNorm).
// ---------------------------------------------------------------------------
__global__ __launch_bounds__(256) void ssd_phaseC(const u16* __restrict__ xconv,
                                                  const u16* __restrict__ zxbcdt,
                                                  const u16* __restrict__ statesT,
                                                  const float* __restrict__ acs_g,
                                                  const float* __restrict__ Dvec,
                                                  u16* __restrict__ ybuf,
                                                  float* __restrict__ normbuf)
{
    const int flat = blockIdx.x + NHEADS*(blockIdx.y + NCHUNK*blockIdx.z);
    const int swzb = (flat & 7) * (BATCH*NCHUNK*NHEADS/8) + (flat >> 3);
    const int h = swzb & (NHEADS-1);
    const int c = (swzb >> 4) & (NCHUNK-1);
    const int b = swzb >> 10;

    const int tid = threadIdx.x;
    const int lane = tid & 63;
    const int w = tid >> 6;
    const int l0 = c * CHUNK;

    __shared__ u16 Ct [64*TS];
    __shared__ u16 SpT[64*TS];
    __shared__ float a_cs[64];

    if (tid < 64) a_cs[tid] = acs_g[(((size_t)b*NCHUNK + c)*NHEADS + h)*CHUNK + tid];
    {
        const int r  = tid >> 2;
        const int q0 = (tid & 3) * 16;
        const u16* cp = xconv + (size_t)(b*SEQLEN + l0 + r)*CONVDIM + DINNER + DSTATE;
        *(uint4*)&Ct[r*TS + q0]     = *(const uint4*)(cp + q0);
        *(uint4*)&Ct[r*TS + q0 + 8] = *(const uint4*)(cp + q0 + 8);
        const u16* spg = statesT + (((size_t)b*NCHUNK + c)*NHEADS + h)*4096 + r*64;
        *(uint4*)&SpT[r*TS + q0]     = *(const uint4*)(spg + q0);
        *(uint4*)&SpT[r*TS + q0 + 8] = *(const uint4*)(spg + q0 + 8);
    }
    __syncthreads();

    const int lrow = lane & 15;
    const int kgrp = lane >> 4;

    f32x4 acc[4] = {};
    #pragma unroll
    for (int ks = 0; ks < 2; ++ks) {
        frag a = *(const frag*)&Ct[(w*16 + lrow)*TS + ks*32 + kgrp*8];
        #pragma unroll
        for (int cf = 0; cf < 4; ++cf) {
            frag bb = *(const frag*)&SpT[(cf*16 + lrow)*TS + ks*32 + kgrp*8];
            acc[cf] = __builtin_amdgcn_mfma_f32_16x16x32_bf16(a, bb, acc[cf], 0, 0, 0);
        }
    }

    const float Dh = Dvec[h];
    #pragma unroll
    for (int r = 0; r < 4; ++r) {
        const int i = w*16 + kgrp*4 + r;
        const int l = l0 + i;
        const float e = __expf(a_cs[i]);
        const u16* xr = xconv  + (size_t)(b*SEQLEN + l)*CONVDIM + h*HEADDIM;
        const u16* zr = zxbcdt + (size_t)(b*SEQLEN + l)*DPROJ   + h*HEADDIM;
        u16* yp = ybuf + (size_t)(b*SEQLEN + l)*DINNER + h*HEADDIM;
        float ssq = 0.f;
        #pragma unroll
        for (int cf = 0; cf < 4; ++cf) {
            const int p = cf*16 + lrow;
            const float yv = bf2f(yp[p]) + e*acc[cf][r] + bf2f(xr[p])*Dh;
            const float zv = bf2f(zr[p]);
            const float fin = yv * (zv / (1.f + __expf(-zv)));
            ssq += fin * fin;
            yp[p] = f2bf(fin);
        }
        // reduce ssq over the 16-lane group (covers 64 cols of this head)
        #pragma unroll
        for (int o = 1; o < 16; o <<= 1) ssq += __shfl_xor(ssq, o, 16);
        if (lrow == 0) atomicAdd(normbuf + (size_t)(b*SEQLEN + l), ssq);
    }
}

// ---------------------------------------------------------------------------
extern "C" void kernel_launch(void* const* d_in, const int* in_sizes, int n_in,
                              void* d_out, int out_size, void* d_ws, size_t ws_size,
                              hipStream_t stream)
{
    const float* u          = (const float*)d_in[0];
    const float* in_proj_w  = (const float*)d_in[1];
    const float* conv_w     = (const float*)d_in[2];
    const float* conv_b     = (const float*)d_in[3];
    const float* dt_bias    = (const float*)d_in[4];
    const float* A_log      = (const float*)d_in[5];
    const float* Dvec       = (const float*)d_in[6];
    const float* norm_w     = (const float*)d_in[7];
    const float* out_proj_w = (const float*)d_in[8];
    float* out = (float*)d_out;

    // workspace layout
    float* acs     = (float*)d_ws;                                 // B*NC*H*CHUNK
    float* asum    = acs  + (size_t)BATCH*NCHUNK*NHEADS*CHUNK;     // B*H*NC
    float* normbuf = asum + (size_t)BATCH*NHEADS*NCHUNK;           // ROWS
    u16* zxbcdt = (u16*)(normbuf + (size_t)ROWS);
    u16* xconv  = zxbcdt + (size_t)ROWS*DPROJ;
    u16* ybuf   = xconv  + (size_t)ROWS*CONVDIM;
    u16* states = ybuf   + (size_t)ROWS*DINNER;                    // B*NC*H*64*64
    u16* w2b    = states + (size_t)BATCH*NCHUNK*NHEADS*DSTATE*HEADDIM;
    // overlay: w1b lives inside states (dead until ssd_phaseA)
    u16* w1b    = states;                          // 2304*256 (zero-padded rows)

    hipMemsetAsync(normbuf, 0, ROWS*sizeof(float), stream);

    cvt_bf16<<<(NPAD1*DMODEL/4+255)/256, 256, 0, stream>>>(in_proj_w, w1b, NPAD1*DMODEL/4, DPROJ, 8);
    cvt_bf16<<<(DMODEL*DINNER/4+255)/256, 256, 0, stream>>>(out_proj_w, w2b, DMODEL*DINNER/4, DMODEL, 10);

    // GEMM1: A = u (fp32, converted at stage), W = w1b
    gemm_mfma<DMODEL, true, false, true><<<dim3(NPAD1/128, ROWS/128), 256, 0, stream>>>(
        u, w1b, zxbcdt, DPROJ, nullptr, nullptr);

    conv_kernel<<<(ROWS*CONVDIM)/256, 256, 0, stream>>>(zxbcdt, conv_w, conv_b, xconv);
    ssd_phaseA<<<dim3(NHEADS, NCHUNK, BATCH), 256, 0, stream>>>(
        xconv, zxbcdt, dt_bias, A_log, ybuf, states, acs, asum);
    ssd_scan<<<BATCH*NHEADS*16, 256, 0, stream>>>(states, asum);
    ssd_phaseC<<<dim3(NHEADS, NCHUNK, BATCH), 256, 0, stream>>>(
        xconv, zxbcdt, states, acs, Dvec, ybuf, normbuf);

    // GEMM2: A = ybuf (bf16) with fused RMSNorm scaling
    gemm_mfma<DINNER, false, true, false><<<dim3(DMODEL/128, ROWS/128), 256, 0, stream>>>(
        ybuf, w2b, out, DMODEL, normbuf, norm_w);
}

// Round 12
// 344.899 us; speedup vs baseline: 1.2301x; 1.1309x over previous
//
#include <hip/hip_runtime.h>
#include <math.h>

#define BATCH   4
#define SEQLEN  4096
#define DMODEL  256
#define DINNER  1024
#define NHEADS  16
#define HEADDIM 64
#define DSTATE  64
#define CONVDIM 1152
#define DPROJ   2192
#define NCHUNK  64
#define CHUNK   64
#define ROWS    (BATCH*SEQLEN)   // 16384
#define NPAD1   2304             // DPROJ padded to multiple of 128
#define TS      72               // padded LDS row stride (u16) for 64-wide tiles
#define CBLK    (CONVDIM/8)      // 144 8-channel chunks per row

typedef unsigned short u16;
using frag  = __attribute__((ext_vector_type(8))) short;   // 8 bf16 (4 VGPRs)
using f32x4 = __attribute__((ext_vector_type(4))) float;
using u32x4 = __attribute__((ext_vector_type(4))) unsigned int;

// bf16 <-> f32 helpers (storage-only precision loss, RNE rounding)
static __device__ __forceinline__ float bf2f(u16 u) {
    return __uint_as_float(((unsigned int)u) << 16);
}
static __device__ __forceinline__ u16 f2bf(float f) {
    unsigned int x = __float_as_uint(f);
    x += 0x7fffu + ((x >> 16) & 1u);
    return (u16)(x >> 16);
}
static __device__ __forceinline__ unsigned int pk2(float lo, float hi) {
    return (unsigned int)f2bf(lo) | ((unsigned int)f2bf(hi) << 16);
}
// non-temporal 16B store (no read-for-ownership, evict-first)
static __device__ __forceinline__ void nt_store16(void* p, uint4 v) {
    u32x4 t = {v.x, v.y, v.z, v.w};
    __builtin_nontemporal_store(t, (u32x4*)p);
}

// ---------------------------------------------------------------------------
// fp32 -> bf16 convert (4 elems/thread). Rows >= valid_rows write zeros
// ---------------------------------------------------------------------------
__global__ __launch_bounds__(256) void cvt_bf16(const float* __restrict__ in,
                                                u16* __restrict__ out,
                                                int total4, int valid_rows, int colshift)
{
    const int i = blockIdx.x * 256 + threadIdx.x;
    if (i >= total4) return;
    const int e = i * 4;
    const int row = e >> colshift;
    ushort4 o;
    if (row < valid_rows) {
        float4 v = *(const float4*)(in + e);
        o.x = f2bf(v.x); o.y = f2bf(v.y); o.z = f2bf(v.z); o.w = f2bf(v.w);
    } else {
        o.x = 0; o.y = 0; o.z = 0; o.w = 0;
    }
    *(ushort4*)(out + e) = o;
}

// ---------------------------------------------------------------------------
// bf16 MFMA GEMM: C[M][N] = A[M][KTOT] @ W[N][KTOT]^T
// 128x128 tile, BK=64, 4 waves. LDS k-slots XOR-swizzled by (row&7).
// XCD-aware bijective block swizzle: blocks sharing an A-panel -> same XCD.
// A_F32: A is fp32, converted to bf16 at LDS-stage (bit-identical to cvt).
// SCALE_A: fused RMSNorm on A rows. All C stores non-temporal.
// ---------------------------------------------------------------------------
template<int KTOT, bool C_BF, bool SCALE_A, bool A_F32>
__global__ __launch_bounds__(256) void gemm_mfma(const void* __restrict__ Ap,
                                                 const u16* __restrict__ W,
                                                 void* __restrict__ Cp,
                                                 int N,
                                                 const float* __restrict__ normv,
                                                 const float* __restrict__ nw)
{
    __shared__ u16 pool[128*136];          // staging uses first 32 KB
    u16* As = pool;
    u16* Ws = pool + 128*64;

    // bijective XCD swizzle (nwg % 8 == 0 for all our grids)
    const int gx   = gridDim.x;
    const int nwg  = gx * gridDim.y;
    const int flat = blockIdx.y * gx + blockIdx.x;
    const int swzb = (flat & 7) * (nwg >> 3) + (flat >> 3);
    const int m0 = (swzb / gx) * 128;
    const int n0 = (swzb % gx) * 128;

    const float* Af = (const float*)Ap;
    const u16*   Ab = (const u16*)Ap;

    const int tid = threadIdx.x;
    const int lane = tid & 63;
    const int w  = tid >> 6;
    const int wr = w >> 1, wc = w & 1;

    const int srow = tid >> 3;             // 0..31
    const int scol = (tid & 7) * 8;        // 0..56
    const int ssw  = scol ^ ((srow & 7) * 8);

    const int lrow = lane & 15;
    const int kgrp = lane >> 4;
    const int swz  = (lrow & 7) * 8;

    float ascale[4];
    if constexpr (SCALE_A) {
        #pragma unroll
        for (int it = 0; it < 4; ++it)
            ascale[it] = rsqrtf(normv[m0 + it*32 + srow] * (1.f/1024.f) + 1e-5f);
    }

    f32x4 acc[4][4] = {};

    uint4 ra[4], rw[4];
    float4 raf[4][2];
    #pragma unroll
    for (int it = 0; it < 4; ++it) {
        const int r = it*32 + srow;
        if constexpr (A_F32) {
            raf[it][0] = *(const float4*)(Af + (size_t)(m0 + r)*KTOT + scol);
            raf[it][1] = *(const float4*)(Af + (size_t)(m0 + r)*KTOT + scol + 4);
        } else {
            ra[it] = *(const uint4*)(Ab + (size_t)(m0 + r)*KTOT + scol);
        }
        rw[it] = *(const uint4*)(W + (size_t)(n0 + r)*KTOT + scol);
    }

    for (int kt = 0; kt < KTOT; kt += 64) {
        __syncthreads();
        #pragma unroll
        for (int it = 0; it < 4; ++it) {
            const int r = it*32 + srow;
            if constexpr (A_F32) {
                uint4 v;
                v.x = pk2(raf[it][0].x, raf[it][0].y);
                v.y = pk2(raf[it][0].z, raf[it][0].w);
                v.z = pk2(raf[it][1].x, raf[it][1].y);
                v.w = pk2(raf[it][1].z, raf[it][1].w);
                *(uint4*)&As[r*64 + ssw] = v;
            } else if constexpr (SCALE_A) {
                uint4 v = ra[it];
                unsigned int* pw = (unsigned int*)&v;
                const float* nwp = nw + kt + scol;
                #pragma unroll
                for (int q = 0; q < 4; ++q) {
                    const float lo = bf2f((u16)(pw[q] & 0xffff)) * ascale[it] * nwp[2*q];
                    const float hi = bf2f((u16)(pw[q] >> 16))    * ascale[it] * nwp[2*q+1];
                    pw[q] = pk2(lo, hi);
                }
                *(uint4*)&As[r*64 + ssw] = v;
            } else {
                *(uint4*)&As[r*64 + ssw] = ra[it];
            }
            *(uint4*)&Ws[r*64 + ssw] = rw[it];
        }
        __syncthreads();
        if (kt + 64 < KTOT) {
            #pragma unroll
            for (int it = 0; it < 4; ++it) {
                const int r = it*32 + srow;
                if constexpr (A_F32) {
                    raf[it][0] = *(const float4*)(Af + (size_t)(m0 + r)*KTOT + kt + 64 + scol);
                    raf[it][1] = *(const float4*)(Af + (size_t)(m0 + r)*KTOT + kt + 64 + scol + 4);
                } else {
                    ra[it] = *(const uint4*)(Ab + (size_t)(m0 + r)*KTOT + kt + 64 + scol);
                }
                rw[it] = *(const uint4*)(W + (size_t)(n0 + r)*KTOT + kt + 64 + scol);
            }
        }
        #pragma unroll
        for (int ks = 0; ks < 2; ++ks) {
            const int kx = (ks*32 + kgrp*8) ^ swz;
            frag af[4], bf[4];
            #pragma unroll
            for (int i = 0; i < 4; ++i)
                af[i] = *(const frag*)&As[(wr*64 + i*16 + lrow)*64 + kx];
            #pragma unroll
            for (int j = 0; j < 4; ++j)
                bf[j] = *(const frag*)&Ws[(wc*64 + j*16 + lrow)*64 + kx];
            #pragma unroll
            for (int i = 0; i < 4; ++i)
                #pragma unroll
                for (int j = 0; j < 4; ++j)
                    acc[i][j] = __builtin_amdgcn_mfma_f32_16x16x32_bf16(af[i], bf[j], acc[i][j], 0, 0, 0);
        }
    }

    if constexpr (C_BF) {
        __syncthreads();
        #pragma unroll
        for (int i = 0; i < 4; ++i)
            #pragma unroll
            for (int j = 0; j < 4; ++j)
                #pragma unroll
                for (int r = 0; r < 4; ++r)
                    pool[(wr*64 + i*16 + kgrp*4 + r)*136 + wc*64 + j*16 + lrow] =
                        f2bf(acc[i][j][r]);
        __syncthreads();
        #pragma unroll
        for (int q = 0; q < 8; ++q) {
            const int f  = q*2048 + tid*8;
            const int rl = f >> 7;
            const int cl = f & 127;
            const int col = n0 + cl;
            if (col < N)
                nt_store16((u16*)Cp + (size_t)(m0 + rl)*N + col,
                           *(const uint4*)&pool[rl*136 + cl]);
        }
    } else {
        #pragma unroll
        for (int i = 0; i < 4; ++i) {
            #pragma unroll
            for (int j = 0; j < 4; ++j) {
                const int col = n0 + wc*64 + j*16 + lrow;
                if (col < N) {
                    #pragma unroll
                    for (int r = 0; r < 4; ++r) {
                        const int row = m0 + wr*64 + i*16 + kgrp*4 + r;
                        __builtin_nontemporal_store(acc[i][j][r],
                            (float*)Cp + (size_t)row * N + col);
                    }
                }
            }
        }
    }
}

// ---------------------------------------------------------------------------
// Depthwise causal conv (W=4) + bias + SiLU — vectorized 8 ch/thread.
// 16B loads for the 4 tap rows, 16B nt store, XCD-swizzled so the +-3-row
// tap overlap hits the same per-XCD L2.
// ---------------------------------------------------------------------------
__global__ __launch_bounds__(256) void conv_kernel(const u16* __restrict__ zxbcdt,
                                                   const float* __restrict__ conv_w,
                                                   const float* __restrict__ conv_b,
                                                   u16* __restrict__ xconv)
{
    const int nwg  = gridDim.x;
    const int flat = blockIdx.x;
    const int d    = (flat & 7) * (nwg >> 3) + (flat >> 3);   // bijective XCD swizzle
    const int idx  = d * 256 + threadIdx.x;                   // 8-channel work unit
    const int ch8  = idx % CBLK;
    const int row  = idx / CBLK;
    const int ch0  = ch8 * 8;
    const int l    = row & (SEQLEN-1);
    const int b    = row >> 12;

    // 4 tap rows, 16B each (zeros before sequence start)
    uint4 rv[4];
    #pragma unroll
    for (int w = 0; w < 4; ++w) {
        const int ls = l - 3 + w;
        if (ls >= 0)
            rv[w] = *(const uint4*)(zxbcdt + (size_t)(b*SEQLEN + ls)*DPROJ + DINNER + ch0);
        else
            rv[w] = make_uint4(0u, 0u, 0u, 0u);
    }

    // weights (4 taps x 8 ch) + bias (8) — small, L2-resident
    float4 cw[8];
    #pragma unroll
    for (int s = 0; s < 8; ++s)
        cw[s] = *(const float4*)(conv_w + (ch0 + s)*4);
    float4 cb0 = *(const float4*)(conv_b + ch0);
    float4 cb1 = *(const float4*)(conv_b + ch0 + 4);
    const float cb[8] = {cb0.x, cb0.y, cb0.z, cb0.w, cb1.x, cb1.y, cb1.z, cb1.w};

    uint4 o;
    unsigned int* ow = (unsigned int*)&o;
    #pragma unroll
    for (int s2 = 0; s2 < 4; ++s2) {       // pairs of channels
        float r01[2];
        #pragma unroll
        for (int half = 0; half < 2; ++half) {
            const int s = s2*2 + half;
            float acc = cb[s];
            #pragma unroll
            for (int w = 0; w < 4; ++w) {
                const unsigned int word = ((const unsigned int*)&rv[w])[s2];
                const u16 e = half ? (u16)(word >> 16) : (u16)(word & 0xffff);
                acc += bf2f(e) * ((const float*)&cw[s])[w];
            }
            r01[half] = acc / (1.f + __expf(-acc));   // SiLU
        }
        ow[s2] = pk2(r01[0], r01[1]);
    }
    nt_store16(xconv + (size_t)row*CONVDIM + ch0, o);
}

// ---------------------------------------------------------------------------
// SSD phase A (MFMA, fused dt/softplus, XCD-swizzled):
//   dt = softplus(zxbcdt[...,-16+h]+bias); dA = -exp(A_log)*dt (wave-0 scan)
//   G = C @ B^T ; M = tril(G)*exp(acs_i - acs_j)
//   Y_diag = M @ xdt -> ybuf ; S^T = xdt^T @ Bscaled -> statesT [p][n]
// Swizzle: all 16 heads of a chunk -> same XCD (B/C tile fetched once/XCD).
// ---------------------------------------------------------------------------
__global__ __launch_bounds__(256) void ssd_phaseA(const u16* __restrict__ xconv,
                                                  const u16* __restrict__ zxbcdt,
                                                  const float* __restrict__ dt_bias,
                                                  const float* __restrict__ A_log,
                                                  u16* __restrict__ ybuf,
                                                  u16* __restrict__ statesT,
                                                  float* __restrict__ acs_g,
                                                  float* __restrict__ asum_g)
{
    const int flat = blockIdx.x + NHEADS*(blockIdx.y + NCHUNK*blockIdx.z);
    const int swzb = (flat & 7) * (BATCH*NCHUNK*NHEADS/8) + (flat >> 3);
    const int h = swzb & (NHEADS-1);
    const int c = (swzb >> 4) & (NCHUNK-1);
    const int b = swzb >> 10;

    const int tid = threadIdx.x;
    const int lane = tid & 63;
    const int w = tid >> 6;
    const int l0 = c * CHUNK;

    __shared__ u16 CtM[64*TS];   // C tile -> M (own rows) -> Y (own rows)
    __shared__ u16 Bt [64*TS];   // B row-major [j][n]
    __shared__ u16 BtT[64*TS];   // decay-scaled B^T [n][j^swz]
    __shared__ u16 xdtT[64*TS];  // (x*dt)^T [p][j^swz] -> S (own rows)
    __shared__ float a_cs[64];
    __shared__ float a_dt[64];

    // fused dt + inclusive cumsum of dA (wave 0)
    if (w == 0) {
        const float raw = bf2f(zxbcdt[(size_t)(b*SEQLEN + l0 + lane)*DPROJ + (DPROJ - NHEADS) + h])
                        + dt_bias[h];
        const float sp = (raw > 20.f) ? raw : log1pf(__expf(raw));
        a_dt[lane] = sp;
        float v = -__expf(A_log[h]) * sp;
        #pragma unroll
        for (int o = 1; o < 64; o <<= 1) {
            float t = __shfl_up(v, o, 64);
            if (lane >= o) v += t;
        }
        a_cs[lane] = v;
    }
    __syncthreads();
    const float a_last = a_cs[63];

    // staging: thread t -> row j = t>>2, 16-col block q0 = (t&3)*16
    {
        const int j  = tid >> 2;
        const int q0 = (tid & 3) * 16;
        const u16* rp = xconv + (size_t)(b*SEQLEN + l0 + j) * CONVDIM;
        const float dtv = a_dt[j];
        const float dec = __expf(a_last - a_cs[j]);

        *(uint4*)&CtM[j*TS + q0]     = *(const uint4*)(rp + DINNER + DSTATE + q0);
        *(uint4*)&CtM[j*TS + q0 + 8] = *(const uint4*)(rp + DINNER + DSTATE + q0 + 8);

        uint4 b0 = *(const uint4*)(rp + DINNER + q0);
        uint4 b1 = *(const uint4*)(rp + DINNER + q0 + 8);
        *(uint4*)&Bt[j*TS + q0]     = b0;
        *(uint4*)&Bt[j*TS + q0 + 8] = b1;
        unsigned int bw[8] = {b0.x, b0.y, b0.z, b0.w, b1.x, b1.y, b1.z, b1.w};
        #pragma unroll
        for (int s = 0; s < 8; ++s) {
            const int n0 = q0 + 2*s, n1 = n0 + 1;
            BtT[n0*TS + (j ^ (n0 & 0x38))] = f2bf(bf2f((u16)(bw[s] & 0xffff)) * dec);
            BtT[n1*TS + (j ^ (n1 & 0x38))] = f2bf(bf2f((u16)(bw[s] >> 16))    * dec);
        }

        uint4 x0 = *(const uint4*)(rp + h*HEADDIM + q0);
        uint4 x1 = *(const uint4*)(rp + h*HEADDIM + q0 + 8);
        unsigned int xw[8] = {x0.x, x0.y, x0.z, x0.w, x1.x, x1.y, x1.z, x1.w};
        #pragma unroll
        for (int s = 0; s < 8; ++s) {
            const int p0 = q0 + 2*s, p1 = p0 + 1;
            xdtT[p0*TS + (j ^ (p0 & 0x38))] = f2bf(bf2f((u16)(xw[s] & 0xffff)) * dtv);
            xdtT[p1*TS + (j ^ (p1 & 0x38))] = f2bf(bf2f((u16)(xw[s] >> 16))    * dtv);
        }
    }
    __syncthreads();

    const int lrow = lane & 15;
    const int kgrp = lane >> 4;

    // ---- G = C @ B^T ----
    f32x4 accG[4] = {};
    #pragma unroll
    for (int ks = 0; ks < 2; ++ks) {
        frag a = *(const frag*)&CtM[(w*16 + lrow)*TS + ks*32 + kgrp*8];
        #pragma unroll
        for (int cf = 0; cf < 4; ++cf) {
            frag bb = *(const frag*)&Bt[(cf*16 + lrow)*TS + ks*32 + kgrp*8];
            accG[cf] = __builtin_amdgcn_mfma_f32_16x16x32_bf16(a, bb, accG[cf], 0, 0, 0);
        }
    }

    // ---- mask + decay -> M over own C rows ----
    {
        float aj[4];
        #pragma unroll
        for (int cf = 0; cf < 4; ++cf) aj[cf] = a_cs[cf*16 + lrow];
        #pragma unroll
        for (int r = 0; r < 4; ++r) {
            const int i = w*16 + kgrp*4 + r;
            const float ai = a_cs[i];
            #pragma unroll
            for (int cf = 0; cf < 4; ++cf) {
                const int jcol = cf*16 + lrow;
                const float g = (jcol <= i) ? accG[cf][r] * __expf(ai - aj[cf]) : 0.f;
                CtM[i*TS + jcol] = f2bf(g);
            }
        }
    }

    // ---- Y_diag = M @ xdt ----
    f32x4 accY[4] = {};
    #pragma unroll
    for (int ks = 0; ks < 2; ++ks) {
        frag a = *(const frag*)&CtM[(w*16 + lrow)*TS + ks*32 + kgrp*8];
        #pragma unroll
        for (int cf = 0; cf < 4; ++cf) {
            const int p = cf*16 + lrow;
            frag bb = *(const frag*)&xdtT[p*TS + ((ks*32 + kgrp*8) ^ (p & 0x38))];
            accY[cf] = __builtin_amdgcn_mfma_f32_16x16x32_bf16(a, bb, accY[cf], 0, 0, 0);
        }
    }
    // Y -> own CtM rows (wave-local; CtM not read by other waves)
    #pragma unroll
    for (int r = 0; r < 4; ++r) {
        const int i = w*16 + kgrp*4 + r;
        #pragma unroll
        for (int cf = 0; cf < 4; ++cf)
            CtM[i*TS + cf*16 + lrow] = f2bf(accY[cf][r]);
    }

    // ---- S^T = xdt^T @ Bscaled ----
    f32x4 accS[4] = {};
    #pragma unroll
    for (int ks = 0; ks < 2; ++ks) {
        const int pr = w*16 + lrow;
        frag a = *(const frag*)&xdtT[pr*TS + ((ks*32 + kgrp*8) ^ (pr & 0x38))];
        #pragma unroll
        for (int cf = 0; cf < 4; ++cf) {
            const int n = cf*16 + lrow;
            frag bb = *(const frag*)&BtT[n*TS + ((ks*32 + kgrp*8) ^ (n & 0x38))];
            accS[cf] = __builtin_amdgcn_mfma_f32_16x16x32_bf16(a, bb, accS[cf], 0, 0, 0);
        }
    }
    __syncthreads();   // all accY/accS xdtT reads complete before overwrite
    #pragma unroll
    for (int r = 0; r < 4; ++r) {
        const int p = w*16 + kgrp*4 + r;
        #pragma unroll
        for (int cf = 0; cf < 4; ++cf)
            xdtT[p*TS + cf*16 + lrow] = f2bf(accS[cf][r]);   // linear [p][n]
    }
    __syncthreads();

    // coalesced nt write-out: Y (from CtM), S (from xdtT)
    {
        const int rr = tid >> 2;
        const int q  = (tid & 3) * 16;
        u16* yg = ybuf + (size_t)(b*SEQLEN + l0 + rr)*DINNER + h*HEADDIM + q;
        nt_store16(yg,     *(const uint4*)&CtM[rr*TS + q]);
        nt_store16(yg + 8, *(const uint4*)&CtM[rr*TS + q + 8]);
        u16* sg = statesT + (((size_t)b*NCHUNK + c)*NHEADS + h)*4096 + tid*16;
        nt_store16(sg,     *(const uint4*)&xdtT[rr*TS + q]);
        nt_store16(sg + 8, *(const uint4*)&xdtT[rr*TS + q + 8]);
    }

    if (tid < 64) acs_g[(((size_t)b*NCHUNK + c)*NHEADS + h)*CHUNK + tid] = a_cs[tid];
    if (tid == 0) asum_g[((size_t)b*NHEADS + h)*NCHUNK + c] = a_last;
}

// ---------------------------------------------------------------------------
// Inter-chunk scan, in place over statesT ([p][n] layout, elementwise)
// ---------------------------------------------------------------------------
__global__ __launch_bounds__(256) void ssd_scan(u16* __restrict__ statesT,
                                                const float* __restrict__ asum_g)
{
    const int gid = blockIdx.x;
    const int s = gid & 15;
    const int h = (gid >> 4) & (NHEADS-1);
    const int b = gid >> 8;
    const int elem = s*256 + threadIdx.x;

    const float* as = asum_g + ((size_t)b*NHEADS + h)*NCHUNK;
    float P = 0.f;
    for (int c = 0; c < NCHUNK; ++c) {
        const size_t idx = (((size_t)b*NCHUNK + c)*NHEADS + h)*4096 + elem;
        const float sv = bf2f(statesT[idx]);
        statesT[idx] = f2bf(P);
        P = P * __expf(as[c]) + sv;
    }
}

// ---------------------------------------------------------------------------
// SSD phase C (MFMA, XCD-swizzled): Y = Y_diag + exp(a_cs)*(C @ Sp) + x*D ;
// y *= silu(z). Accumulates per-row sum(y^2) into normbuf (fused RMSNorm).
// ---------------------------------------------------------------------------
__global__ __launch_bounds__(256) void ssd_phaseC(const u16* __restrict__ xconv,
                                                  const u16* __restrict__ zxbcdt,
                                                  const u16* __restrict__ statesT,
                                                  const float* __restrict__ acs_g,
                                                  const float* __restrict__ Dvec,
                                                  u16* __restrict__ ybuf,
                                                  float* __restrict__ normbuf)
{
    const int flat = blockIdx.x + NHEADS*(blockIdx.y + NCHUNK*blockIdx.z);
    const int swzb = (flat & 7) * (BATCH*NCHUNK*NHEADS/8) + (flat >> 3);
    const int h = swzb & (NHEADS-1);
    const int c = (swzb >> 4) & (NCHUNK-1);
    const int b = swzb >> 10;

    const int tid = threadIdx.x;
    const int lane = tid & 63;
    const int w = tid >> 6;
    const int l0 = c * CHUNK;

    __shared__ u16 Ct [64*TS];
    __shared__ u16 SpT[64*TS];
    __shared__ float a_cs[64];

    if (tid < 64) a_cs[tid] = acs_g[(((size_t)b*NCHUNK + c)*NHEADS + h)*CHUNK + tid];
    {
        const int r  = tid >> 2;
        const int q0 = (tid & 3) * 16;
        const u16* cp = xconv + (size_t)(b*SEQLEN + l0 + r)*CONVDIM + DINNER + DSTATE;
        *(uint4*)&Ct[r*TS + q0]     = *(const uint4*)(cp + q0);
        *(uint4*)&Ct[r*TS + q0 + 8] = *(const uint4*)(cp + q0 + 8);
        const u16* spg = statesT + (((size_t)b*NCHUNK + c)*NHEADS + h)*4096 + r*64;
        *(uint4*)&SpT[r*TS + q0]     = *(const uint4*)(spg + q0);
        *(uint4*)&SpT[r*TS + q0 + 8] = *(const uint4*)(spg + q0 + 8);
    }
    __syncthreads();

    const int lrow = lane & 15;
    const int kgrp = lane >> 4;

    f32x4 acc[4] = {};
    #pragma unroll
    for (int ks = 0; ks < 2; ++ks) {
        frag a = *(const frag*)&Ct[(w*16 + lrow)*TS + ks*32 + kgrp*8];
        #pragma unroll
        for (int cf = 0; cf < 4; ++cf) {
            frag bb = *(const frag*)&SpT[(cf*16 + lrow)*TS + ks*32 + kgrp*8];
            acc[cf] = __builtin_amdgcn_mfma_f32_16x16x32_bf16(a, bb, acc[cf], 0, 0, 0);
        }
    }

    const float Dh = Dvec[h];
    #pragma unroll
    for (int r = 0; r < 4; ++r) {
        const int i = w*16 + kgrp*4 + r;
        const int l = l0 + i;
        const float e = __expf(a_cs[i]);
        const u16* xr = xconv  + (size_t)(b*SEQLEN + l)*CONVDIM + h*HEADDIM;
        const u16* zr = zxbcdt + (size_t)(b*SEQLEN + l)*DPROJ   + h*HEADDIM;
        u16* yp = ybuf + (size_t)(b*SEQLEN + l)*DINNER + h*HEADDIM;
        float ssq = 0.f;
        #pragma unroll
        for (int cf = 0; cf < 4; ++cf) {
            const int p = cf*16 + lrow;
            const float yv = bf2f(yp[p]) + e*acc[cf][r] + bf2f(xr[p])*Dh;
            const float zv = bf2f(zr[p]);
            const float fin = yv * (zv / (1.f + __expf(-zv)));
            ssq += fin * fin;
            yp[p] = f2bf(fin);
        }
        // reduce ssq over the 16-lane group (covers 64 cols of this head)
        #pragma unroll
        for (int o = 1; o < 16; o <<= 1) ssq += __shfl_xor(ssq, o, 16);
        if (lrow == 0) atomicAdd(normbuf + (size_t)(b*SEQLEN + l), ssq);
    }
}

// ---------------------------------------------------------------------------
extern "C" void kernel_launch(void* const* d_in, const int* in_sizes, int n_in,
                              void* d_out, int out_size, void* d_ws, size_t ws_size,
                              hipStream_t stream)
{
    const float* u          = (const float*)d_in[0];
    const float* in_proj_w  = (const float*)d_in[1];
    const float* conv_w     = (const float*)d_in[2];
    const float* conv_b     = (const float*)d_in[3];
    const float* dt_bias    = (const float*)d_in[4];
    const float* A_log      = (const float*)d_in[5];
    const float* Dvec       = (const float*)d_in[6];
    const float* norm_w     = (const float*)d_in[7];
    const float* out_proj_w = (const float*)d_in[8];
    float* out = (float*)d_out;

    // workspace layout
    float* acs     = (float*)d_ws;                                 // B*NC*H*CHUNK
    float* asum    = acs  + (size_t)BATCH*NCHUNK*NHEADS*CHUNK;     // B*H*NC
    float* normbuf = asum + (size_t)BATCH*NHEADS*NCHUNK;           // ROWS
    u16* zxbcdt = (u16*)(normbuf + (size_t)ROWS);
    u16* xconv  = zxbcdt + (size_t)ROWS*DPROJ;
    u16* ybuf   = xconv  + (size_t)ROWS*CONVDIM;
    u16* states = ybuf   + (size_t)ROWS*DINNER;                    // B*NC*H*64*64
    u16* w2b    = states + (size_t)BATCH*NCHUNK*NHEADS*DSTATE*HEADDIM;
    // overlay: w1b lives inside states (dead until ssd_phaseA)
    u16* w1b    = states;                          // 2304*256 (zero-padded rows)

    hipMemsetAsync(normbuf, 0, ROWS*sizeof(float), stream);

    cvt_bf16<<<(NPAD1*DMODEL/4+255)/256, 256, 0, stream>>>(in_proj_w, w1b, NPAD1*DMODEL/4, DPROJ, 8);
    cvt_bf16<<<(DMODEL*DINNER/4+255)/256, 256, 0, stream>>>(out_proj_w, w2b, DMODEL*DINNER/4, DMODEL, 10);

    // GEMM1: A = u (fp32, converted at stage), W = w1b
    gemm_mfma<DMODEL, true, false, true><<<dim3(NPAD1/128, ROWS/128), 256, 0, stream>>>(
        u, w1b, zxbcdt, DPROJ, nullptr, nullptr);

    conv_kernel<<<(ROWS*CBLK)/256, 256, 0, stream>>>(zxbcdt, conv_w, conv_b, xconv);
    ssd_phaseA<<<dim3(NHEADS, NCHUNK, BATCH), 256, 0, stream>>>(
        xconv, zxbcdt, dt_bias, A_log, ybuf, states, acs, asum);
    ssd_scan<<<BATCH*NHEADS*16, 256, 0, stream>>>(states, asum);
    ssd_phaseC<<<dim3(NHEADS, NCHUNK, BATCH), 256, 0, stream>>>(
        xconv, zxbcdt, states, acs, Dvec, ybuf, normbuf);

    // GEMM2: A = ybuf (bf16) with fused RMSNorm scaling
    gemm_mfma<DINNER, false, true, false><<<dim3(DMODEL/128, ROWS/128), 256, 0, stream>>>(
        ybuf, w2b, out, DMODEL, normbuf, norm_w);
}